// Round 1
// baseline (737.766 us; speedup 1.0000x reference)
//
#include <hip/hip_runtime.h>
#include <stddef.h>

#define BS 8192
#define NNODE 25
#define TT 128

// Static device buffers: avoids any dependence on ws_size. Fully rewritten
// every call (transpose writes all of g_xT; rnn writes all of g_hf/g_hb).
__device__ float g_xT[(size_t)TT * NNODE * BS];   // (t, i, b)  ~105 MB
__device__ float g_hf[NNODE * BS * 4];            // (i, b, d)
__device__ float g_hb[NNODE * BS * 4];

// Broadcast lane K of each quad (lanes 4q..4q+3) via DPP quad_perm — 1 inst, no LDS.
template <int K>
__device__ __forceinline__ float bcast4(float v) {
  int s = __builtin_bit_cast(int, v);
  int r = __builtin_amdgcn_update_dpp(0, s, (K * 0x55), 0xF, 0xF, true);
  return __builtin_bit_cast(float, r);
}

__device__ __forceinline__ float fsig(float x) {
  float e = __expf(-x);                       // v_mul + v_exp
  return __builtin_amdgcn_rcpf(1.0f + e);     // v_add + v_rcp
}
__device__ __forceinline__ float ftanh_(float x) {
  // tanh(x) = 1 - 2/(exp(2x)+1); saturates correctly at +/-inf.
  float e = __expf(2.0f * x);
  return fmaf(-2.0f, __builtin_amdgcn_rcpf(1.0f + e), 1.0f);
}

// x (b, i, t) -> g_xT (t, i, b): 25 independent 8192x128 transposes, 32x32 tiles.
__global__ __launch_bounds__(256) void transpose_x(const float* __restrict__ x) {
  __shared__ float tile[32][33];
  const int i = blockIdx.z;
  const int b0 = blockIdx.x * 32;
  const int t0 = blockIdx.y * 32;
  const int tx = threadIdx.x;  // 0..31
  const int ty = threadIdx.y;  // 0..7
#pragma unroll
  for (int j = 0; j < 4; ++j) {
    int bl = ty + j * 8;
    tile[bl][tx] = x[((size_t)(b0 + bl) * NNODE + i) * TT + (t0 + tx)];
  }
  __syncthreads();
#pragma unroll
  for (int j = 0; j < 4; ++j) {
    int tl = ty + j * 8;
    g_xT[((size_t)(t0 + tl) * NNODE + i) * BS + (b0 + tx)] = tile[tx][tl];
  }
}

// Quad scheme: 4 lanes per (batch-elem, direction). Lane d owns feature d of all
// nodes' h/c and the weight columns for gates {d, 4+d, 8+d, 12+d}.
// grid (128, 2) x block 256: b = blockIdx.x*64 + tid/4, dir = blockIdx.y.
__global__ __launch_bounds__(256, 1) void rnn_kernel(
    const float* __restrict__ h0f, const float* __restrict__ c0f,
    const float* __restrict__ h0b, const float* __restrict__ c0b,
    const float* __restrict__ Wxf, const float* __restrict__ Whf,
    const float* __restrict__ Wnf, const float* __restrict__ bf,
    const float* __restrict__ Wxb, const float* __restrict__ Whb,
    const float* __restrict__ Wnb, const float* __restrict__ bb_) {
  const int dir = blockIdx.y;
  const int d = threadIdx.x & 3;
  const int b = blockIdx.x * 64 + (threadIdx.x >> 2);

  const float* Wx = dir ? Wxb : Wxf;
  const float* Wh = dir ? Whb : Whf;
  const float* Wn = dir ? Wnb : Wnf;
  const float* Bb = dir ? bb_ : bf;
  const float* h0 = dir ? h0b : h0f;
  const float* c0 = dir ? c0b : c0f;

  // Per-lane weight columns. Neighbor order: fwd [up,dn,lf,rt], bwd [up,dn,rt,lf]
  // -> for bwd, weight row for the lf-value is Wn row 3 and rt-value is row 2.
  float wx[4], wb[4], wh[4][4], wn[4][4];
#pragma unroll
  for (int q = 0; q < 4; ++q) {
    const int g = q * 4 + d;
    wx[q] = Wx[g];
    wb[q] = Bb[g];
#pragma unroll
    for (int k = 0; k < 4; ++k) wh[q][k] = Wh[k * 16 + g];
    wn[q][0] = Wn[0 * 16 + g];
    wn[q][1] = Wn[1 * 16 + g];
    wn[q][2] = Wn[(dir ? 3 : 2) * 16 + g];
    wn[q][3] = Wn[(dir ? 2 : 3) * 16 + g];
  }

  float h[NNODE], c[NNODE];
#pragma unroll
  for (int i = 0; i < NNODE; ++i) {
    h[i] = h0[(i * BS + b) * 4 + d];
    c[i] = c0[(i * BS + b) * 4 + d];
  }

  // x base: fwd walks t=0..127, bwd walks t=127..0 (reversed sequence).
  const float* xbase = g_xT + ((size_t)(dir ? (TT - 1) : 0) * NNODE * BS);
  const ptrdiff_t xstep = dir ? -(ptrdiff_t)(NNODE * BS) : (ptrdiff_t)(NNODE * BS);

  for (int t = 0; t < TT; ++t) {
    // Issue all 25 x loads up front; node i first uses xv[i] well after issue.
    float xv[NNODE];
#pragma unroll
    for (int i = 0; i < NNODE; ++i) xv[i] = xbase[(size_t)i * BS + b];

#pragma unroll
    for (int i = 0; i < NNODE; ++i) {
      // Own hidden features, broadcast from lanes 0..3 of the quad.
      const float f0 = bcast4<0>(h[i]);
      const float f1 = bcast4<1>(h[i]);
      const float f2 = bcast4<2>(h[i]);
      const float f3 = bcast4<3>(h[i]);
      // Neighbor feature-3 (lane 3). up/lf already updated this t (j<i);
      // dn/rt still hold previous-t values (j>i) — matches reference order.
      // lf/rt intentionally row-wrap (faithful to reference's missing col check).
      const float n0 = (i >= 5) ? bcast4<3>(h[i - 5]) : 0.0f;  // up
      const float n1 = (i < 20) ? bcast4<3>(h[i + 5]) : 0.0f;  // dn
      const float n2 = (i >= 1) ? bcast4<3>(h[i - 1]) : 0.0f;  // lf
      const float n3 = (i < 24) ? bcast4<3>(h[i + 1]) : 0.0f;  // rt

      float g[4];
#pragma unroll
      for (int q = 0; q < 4; ++q) {
        float acc = fmaf(xv[i], wx[q], wb[q]);
        acc = fmaf(f0, wh[q][0], acc);
        acc = fmaf(f1, wh[q][1], acc);
        acc = fmaf(f2, wh[q][2], acc);
        acc = fmaf(f3, wh[q][3], acc);
        acc = fmaf(n0, wn[q][0], acc);
        acc = fmaf(n1, wn[q][1], acc);
        acc = fmaf(n2, wn[q][2], acc);
        acc = fmaf(n3, wn[q][3], acc);
        g[q] = acc;
      }
      const float si = fsig(g[0]);
      const float sf = fsig(g[1]);
      const float so = fsig(g[2]);
      const float tc = ftanh_(g[3]);
      const float nc = fmaf(sf, c[i], si * tc);
      c[i] = nc;
      h[i] = so * ftanh_(nc);
    }
    xbase += xstep;
  }

  float* ho = dir ? g_hb : g_hf;
#pragma unroll
  for (int i = 0; i < NNODE; ++i) ho[(i * BS + b) * 4 + d] = h[i];
}

// H(b,200) -> sigmoid(H@Wff+bff) -> softmax(ff@Wout+bout). Block = 128 threads,
// 8 batch elems per block (reuses each Wff element 8x).
__global__ __launch_bounds__(128) void ff_kernel(
    const float* __restrict__ Wff, const float* __restrict__ bff,
    const float* __restrict__ Wout, const float* __restrict__ bout,
    float* __restrict__ out) {
  __shared__ float Hs[8][200];
  __shared__ float ffs[8][129];
  const int tid = threadIdx.x;
  const int b0 = blockIdx.x * 8;

  for (int idx = tid; idx < 8 * 200; idx += 128) {
    const int bb = idx / 200;
    const int k = idx - bb * 200;
    const int i = k >> 3;
    const int dd = k & 7;
    const int b = b0 + bb;
    Hs[bb][k] = (dd < 4) ? g_hf[(i * BS + b) * 4 + dd]
                         : g_hb[(i * BS + b) * 4 + (dd - 4)];
  }
  __syncthreads();

  float acc[8];
  const float bv = bff[tid];
#pragma unroll
  for (int bb = 0; bb < 8; ++bb) acc[bb] = bv;
  for (int k = 0; k < 200; ++k) {
    const float w = Wff[k * 128 + tid];  // coalesced; Hs[bb][k] is LDS broadcast
#pragma unroll
    for (int bb = 0; bb < 8; ++bb) acc[bb] = fmaf(Hs[bb][k], w, acc[bb]);
  }
#pragma unroll
  for (int bb = 0; bb < 8; ++bb) ffs[bb][tid] = fsig(acc[bb]);
  __syncthreads();

  if (tid < 8) {
    float z0 = bout[0], z1 = bout[1];
    for (int n = 0; n < 128; ++n) {
      const float f = ffs[tid][n];
      z0 = fmaf(f, Wout[n * 2 + 0], z0);
      z1 = fmaf(f, Wout[n * 2 + 1], z1);
    }
    const float m = fmaxf(z0, z1);
    const float e0 = __expf(z0 - m), e1 = __expf(z1 - m);
    const float s = __builtin_amdgcn_rcpf(e0 + e1);
    out[(size_t)(b0 + tid) * 2 + 0] = e0 * s;
    out[(size_t)(b0 + tid) * 2 + 1] = e1 * s;
  }
}

extern "C" void kernel_launch(void* const* d_in, const int* in_sizes, int n_in,
                              void* d_out, int out_size, void* d_ws, size_t ws_size,
                              hipStream_t stream) {
  (void)in_sizes; (void)n_in; (void)out_size; (void)d_ws; (void)ws_size;
  const float* x    = (const float*)d_in[0];
  const float* h0f  = (const float*)d_in[1];
  const float* c0f  = (const float*)d_in[2];
  const float* h0b  = (const float*)d_in[3];
  const float* c0b  = (const float*)d_in[4];
  const float* Wxf  = (const float*)d_in[5];
  const float* Whf  = (const float*)d_in[6];
  const float* Wnf  = (const float*)d_in[7];
  const float* bf   = (const float*)d_in[8];
  const float* Wxb  = (const float*)d_in[9];
  const float* Whb  = (const float*)d_in[10];
  const float* Wnb  = (const float*)d_in[11];
  const float* bb   = (const float*)d_in[12];
  const float* Wff  = (const float*)d_in[13];
  const float* bff  = (const float*)d_in[14];
  const float* Wout = (const float*)d_in[15];
  const float* bout = (const float*)d_in[16];
  float* out = (float*)d_out;

  transpose_x<<<dim3(256, 4, 25), dim3(32, 8), 0, stream>>>(x);
  rnn_kernel<<<dim3(128, 2), dim3(256), 0, stream>>>(
      h0f, c0f, h0b, c0b, Wxf, Whf, Wnf, bf, Wxb, Whb, Wnb, bb);
  ff_kernel<<<dim3(1024), dim3(128), 0, stream>>>(Wff, bff, Wout, bout, out);
}